// Round 2
// baseline (297.413 us; speedup 1.0000x reference)
//
#include <hip/hip_runtime.h>
#include <math.h>

// DiceLoss: B=8, C=19, H=W=512. logits fp32 [B,C,H,W], targets int [B,H,W].
// Round 9: two-pass softmax for long per-channel bursts.
// History: R7 nt-load null (L1 policy irrelevant), R8 in-flight-limiting null
// (outstanding congruent-stream count irrelevant). Remaining suspect for the
// 1.87 TB/s wall (accum ~90us for 160 MiB, floor ~25us): per-channel burst
// LENGTH. Old structure (x[19] in VGPRs) forces 1 KiB/channel/wave before a
// 2^20-byte plane hop -> same-bank row/page switch every KiB. New structure:
// 16 px/thread, two passes.
//   Pass 1: for c=0..18 stream 4 KiB/wave/channel contiguous, accumulate
//           per-pixel denom s (channel order ascending -> FP order preserved).
//   Pass 2: re-stream same addresses (L3-resident: 160 MiB < 256 MiB L3 and
//           all 512 blocks co-resident -> stream never evicts itself),
//           compute exp(x)*rcp(s), accumulate S/I/C.
// Plain cached loads everywhere (pass 2 needs the L3 allocation from pass 1).

#define CC 19
#define QPP 65536              // f32x4 quads per channel plane (2^16)
#define NQUAD 524288           // total quads (2^19)
#define NBLK 512
#define NTHR 256
#define QPB 1024               // quads per block tile (NQUAD/NBLK), 4096 px
#define IGNORE_IDX 255

typedef float f32x4 __attribute__((ext_vector_type(4)));
typedef int   i32x4 __attribute__((ext_vector_type(4)));

__device__ __forceinline__ f32x4 exp4(f32x4 v) {
    f32x4 r;
    r.x = __expf(v.x); r.y = __expf(v.y);
    r.z = __expf(v.z); r.w = __expf(v.w);
    return r;
}

__global__ __launch_bounds__(NTHR, 2) void dice_accum(
    const float* __restrict__ logits,
    const int* __restrict__ targets,
    float* __restrict__ part)         // part[NBLK][64]: 0-18 S, 19-37 I, 38-56 cnt
{
    const int lane = threadIdx.x & 63;
    const int wv   = threadIdx.x >> 6;                      // 0..3
    const int q0   = blockIdx.x * QPB + wv * 256 + lane;    // first quad
    const int b    = q0 >> 16;                              // batch plane
    const int hw4  = q0 & (QPP - 1);
    const f32x4* bbase = (const f32x4*)logits + (size_t)b * (CC * QPP) + hw4;
    // thread's 4 quad-groups at +0,+64,+128,+192 quads (wave = 4 KiB contiguous/channel)

    // targets for the 16 px (resident across both passes)
    const i32x4* tq = (const i32x4*)targets;
    const i32x4 t0 = tq[q0];
    const i32x4 t1 = tq[q0 + 64];
    const i32x4 t2 = tq[q0 + 128];
    const i32x4 t3 = tq[q0 + 192];

    // ---- pass 1: per-pixel softmax denominators (channel order 0..18) ----
    f32x4 s0 = {0.f,0.f,0.f,0.f}, s1 = {0.f,0.f,0.f,0.f};
    f32x4 s2 = {0.f,0.f,0.f,0.f}, s3 = {0.f,0.f,0.f,0.f};
#pragma unroll
    for (int c = 0; c < CC; ++c) {
        const f32x4* p = bbase + (size_t)c * QPP;
        s0 += exp4(p[0]);
        s1 += exp4(p[64]);
        s2 += exp4(p[128]);
        s3 += exp4(p[192]);
    }

    // reciprocal denominators, zeroed for ignored pixels
    f32x4 i0, i1, i2, i3;
    i0.x = (t0.x != IGNORE_IDX) ? __builtin_amdgcn_rcpf(s0.x) : 0.f;
    i0.y = (t0.y != IGNORE_IDX) ? __builtin_amdgcn_rcpf(s0.y) : 0.f;
    i0.z = (t0.z != IGNORE_IDX) ? __builtin_amdgcn_rcpf(s0.z) : 0.f;
    i0.w = (t0.w != IGNORE_IDX) ? __builtin_amdgcn_rcpf(s0.w) : 0.f;
    i1.x = (t1.x != IGNORE_IDX) ? __builtin_amdgcn_rcpf(s1.x) : 0.f;
    i1.y = (t1.y != IGNORE_IDX) ? __builtin_amdgcn_rcpf(s1.y) : 0.f;
    i1.z = (t1.z != IGNORE_IDX) ? __builtin_amdgcn_rcpf(s1.z) : 0.f;
    i1.w = (t1.w != IGNORE_IDX) ? __builtin_amdgcn_rcpf(s1.w) : 0.f;
    i2.x = (t2.x != IGNORE_IDX) ? __builtin_amdgcn_rcpf(s2.x) : 0.f;
    i2.y = (t2.y != IGNORE_IDX) ? __builtin_amdgcn_rcpf(s2.y) : 0.f;
    i2.z = (t2.z != IGNORE_IDX) ? __builtin_amdgcn_rcpf(s2.z) : 0.f;
    i2.w = (t2.w != IGNORE_IDX) ? __builtin_amdgcn_rcpf(s2.w) : 0.f;
    i3.x = (t3.x != IGNORE_IDX) ? __builtin_amdgcn_rcpf(s3.x) : 0.f;
    i3.y = (t3.y != IGNORE_IDX) ? __builtin_amdgcn_rcpf(s3.y) : 0.f;
    i3.z = (t3.z != IGNORE_IDX) ? __builtin_amdgcn_rcpf(s3.z) : 0.f;
    i3.w = (t3.w != IGNORE_IDX) ? __builtin_amdgcn_rcpf(s3.w) : 0.f;

    // ---- pass 2: re-stream (L3-hot), accumulate S / I / C ----
    float accS[CC], accI[CC], accC[CC];
#pragma unroll
    for (int c = 0; c < CC; ++c) { accS[c] = 0.f; accI[c] = 0.f; accC[c] = 0.f; }

#pragma unroll
    for (int c = 0; c < CC; ++c) {
        const f32x4* p = bbase + (size_t)c * QPP;
        const f32x4 eA = exp4(p[0]);
        const f32x4 eB = exp4(p[64]);
        const f32x4 eC = exp4(p[128]);
        const f32x4 eD = exp4(p[192]);

        accS[c] = fmaf(eA.x, i0.x, fmaf(eA.y, i0.y, fmaf(eA.z, i0.z, fmaf(eA.w, i0.w,
                  fmaf(eB.x, i1.x, fmaf(eB.y, i1.y, fmaf(eB.z, i1.z, fmaf(eB.w, i1.w,
                  fmaf(eC.x, i2.x, fmaf(eC.y, i2.y, fmaf(eC.z, i2.z, fmaf(eC.w, i2.w,
                  fmaf(eD.x, i3.x, fmaf(eD.y, i3.y, fmaf(eD.z, i3.z, fmaf(eD.w, i3.w,
                  accS[c]))))))))))))))));

        accI[c] = fmaf((t0.x == c) ? eA.x : 0.f, i0.x,
                  fmaf((t0.y == c) ? eA.y : 0.f, i0.y,
                  fmaf((t0.z == c) ? eA.z : 0.f, i0.z,
                  fmaf((t0.w == c) ? eA.w : 0.f, i0.w,
                  fmaf((t1.x == c) ? eB.x : 0.f, i1.x,
                  fmaf((t1.y == c) ? eB.y : 0.f, i1.y,
                  fmaf((t1.z == c) ? eB.z : 0.f, i1.z,
                  fmaf((t1.w == c) ? eB.w : 0.f, i1.w,
                  fmaf((t2.x == c) ? eC.x : 0.f, i2.x,
                  fmaf((t2.y == c) ? eC.y : 0.f, i2.y,
                  fmaf((t2.z == c) ? eC.z : 0.f, i2.z,
                  fmaf((t2.w == c) ? eC.w : 0.f, i2.w,
                  fmaf((t3.x == c) ? eD.x : 0.f, i3.x,
                  fmaf((t3.y == c) ? eD.y : 0.f, i3.y,
                  fmaf((t3.z == c) ? eD.z : 0.f, i3.z,
                  fmaf((t3.w == c) ? eD.w : 0.f, i3.w,
                  accI[c]))))))))))))))));

        accC[c] += ((t0.x == c) ? 1.f : 0.f) + ((t0.y == c) ? 1.f : 0.f)
                 + ((t0.z == c) ? 1.f : 0.f) + ((t0.w == c) ? 1.f : 0.f)
                 + ((t1.x == c) ? 1.f : 0.f) + ((t1.y == c) ? 1.f : 0.f)
                 + ((t1.z == c) ? 1.f : 0.f) + ((t1.w == c) ? 1.f : 0.f)
                 + ((t2.x == c) ? 1.f : 0.f) + ((t2.y == c) ? 1.f : 0.f)
                 + ((t2.z == c) ? 1.f : 0.f) + ((t2.w == c) ? 1.f : 0.f)
                 + ((t3.x == c) ? 1.f : 0.f) + ((t3.y == c) ? 1.f : 0.f)
                 + ((t3.z == c) ? 1.f : 0.f) + ((t3.w == c) ? 1.f : 0.f);
    }

    // ---- wave-level reduce of the 57 accumulators ----
#pragma unroll
    for (int c = 0; c < CC; ++c) {
        for (int off = 32; off; off >>= 1) {
            accS[c] += __shfl_down(accS[c], off);
            accI[c] += __shfl_down(accI[c], off);
            accC[c] += __shfl_down(accC[c], off);
        }
    }

    __shared__ float s_part[4][64];
    if (lane == 0) {
#pragma unroll
        for (int c = 0; c < CC; ++c) {
            s_part[wv][c]          = accS[c];
            s_part[wv][CC + c]     = accI[c];
            s_part[wv][2 * CC + c] = accC[c];
        }
#pragma unroll
        for (int c = 3 * CC; c < 64; ++c) s_part[wv][c] = 0.f;  // ws is poisoned
    }
    __syncthreads();
    if (threadIdx.x < 64) {
        float v = s_part[0][threadIdx.x] + s_part[1][threadIdx.x]
                + s_part[2][threadIdx.x] + s_part[3][threadIdx.x];
        part[blockIdx.x * 64 + threadIdx.x] = v;
    }
}

__global__ __launch_bounds__(1024) void dice_final(
    const float* __restrict__ part, float* __restrict__ out)
{
    const int wave = threadIdx.x >> 6;   // 0..15
    const int lane = threadIdx.x & 63;
    float v = 0.f;
    for (int r = wave; r < NBLK; r += 16)
        v += part[r * 64 + lane];        // coalesced 256B rows

    __shared__ float s_red[16][64];
    s_red[wave][lane] = v;
    __syncthreads();

    __shared__ float s_tot[64];
    if (threadIdx.x < 64) {
        float tot = 0.f;
#pragma unroll
        for (int w = 0; w < 16; ++w) tot += s_red[w][threadIdx.x];
        s_tot[threadIdx.x] = tot;
    }
    __syncthreads();

    if (threadIdx.x == 0) {
        float loss = 0.f, totv = 0.f;
#pragma unroll
        for (int c = 0; c < CC; ++c) {
            const float S = s_tot[c];
            const float I = s_tot[CC + c];
            const float N = s_tot[2 * CC + c];
            totv += N;
            loss += 1.f - (2.f * I + 1.f) / (S + N + 1.f);
        }
        out[0] = (totv > 0.f) ? loss * (1.f / (float)CC) : 0.f;
    }
}

extern "C" void kernel_launch(void* const* d_in, const int* in_sizes, int n_in,
                              void* d_out, int out_size, void* d_ws, size_t ws_size,
                              hipStream_t stream) {
    const float* logits = (const float*)d_in[0];
    const int* targets = (const int*)d_in[1];
    float* part = (float*)d_ws;          // 512*64*4 = 128 KB
    float* out = (float*)d_out;

    dice_accum<<<NBLK, NTHR, 0, stream>>>(logits, targets, part);
    dice_final<<<1, 1024, 0, stream>>>(part, out);
}

// Round 3
// 229.375 us; speedup vs baseline: 1.2966x; 1.2966x over previous
//
#include <hip/hip_runtime.h>
#include <math.h>

// DiceLoss: B=8, C=19, H=W=512. logits fp32 [B,C,H,W], targets int [B,H,W].
// Round 10: sustained-outstanding-reads + cheap final.
// Dead theories: L1 policy (R7 null), outstanding-count limiting (R8 -3%),
// burst length (R9: 2-pass slower, occupancy-starved).
// Live theory: read BW = avg outstanding bytes/CU / ~375ns. All prior
// kernels burst-issue 20 loads then DRAIN to zero while ~500cy of VALU
// consumes them -> duty ~50-60% of the per-CU miss-concurrency cap.
// Fix A: cross-iteration register double-buffer at 2 px/thread (f32x2):
//   issue iter t+1's 19+1 loads BEFORE consuming iter t. Each wave then
//   holds >=19 loads (9.5 KiB) in flight through every compute phase.
//   VGPR: 2x38 buf + 57 acc + misc ~ 160 -> 3 waves/SIMD, 1024 blocks.
// Fix B: dice_final was 1 block reading 256 KB from ONE CU (~30us hidden).
//   Replace with per-block atomicAdd into 64 floats (ws memset to 0), final
//   kernel reads 57 floats (~2us).

#define CC 19
#define HPP 131072                    // f32x2 elements per channel plane (2^17)
#define NBLK 1024
#define NTHR 256
#define NTH_TOT (NBLK * NTHR)         // 262144 threads
#define NITER 4                       // 262144*2px*4 = 2,097,152 px exact
#define IGNORE_IDX 255

typedef float f32x2 __attribute__((ext_vector_type(2)));
typedef int   i32x2 __attribute__((ext_vector_type(2)));

__device__ __forceinline__ void issue_tile(
    f32x2 (&x)[CC], i32x2& t,
    const float* __restrict__ logits, const int* __restrict__ targets, int hq)
{
    const int b   = hq >> 17;                 // batch plane
    const int hw2 = hq & (HPP - 1);
    const f32x2* base = (const f32x2*)logits + ((size_t)b * CC) * HPP + hw2;
#pragma unroll
    for (int c = 0; c < CC; ++c)
        x[c] = __builtin_nontemporal_load(base + (size_t)c * HPP);
    t = __builtin_nontemporal_load((const i32x2*)targets + hq);
    __builtin_amdgcn_sched_barrier(0);        // pin: all loads issued before consume
}

__device__ __forceinline__ void proc_tile(
    f32x2 (&x)[CC], const i32x2 t,
    float (&accS)[CC], float (&accI)[CC], float (&accC)[CC])
{
    float s0 = 0.f, s1 = 0.f;
#pragma unroll
    for (int c = 0; c < CC; ++c) {            // in-place exp, channel order 0..18
        x[c].x = __expf(x[c].x); s0 += x[c].x;
        x[c].y = __expf(x[c].y); s1 += x[c].y;
    }
    const float i0 = (t.x != IGNORE_IDX) ? __builtin_amdgcn_rcpf(s0) : 0.f;
    const float i1 = (t.y != IGNORE_IDX) ? __builtin_amdgcn_rcpf(s1) : 0.f;
#pragma unroll
    for (int c = 0; c < CC; ++c) {
        accS[c] = fmaf(x[c].x, i0, fmaf(x[c].y, i1, accS[c]));
        const bool h0 = (t.x == c), h1 = (t.y == c);
        accI[c] = fmaf(h0 ? x[c].x : 0.f, i0,
                  fmaf(h1 ? x[c].y : 0.f, i1, accI[c]));
        accC[c] += (h0 ? 1.f : 0.f) + (h1 ? 1.f : 0.f);
    }
}

__global__ __launch_bounds__(NTHR, 2) void dice_accum(
    const float* __restrict__ logits,
    const int* __restrict__ targets,
    float* __restrict__ sums)                 // sums[64]: 0-18 S, 19-37 I, 38-56 cnt
{
    const int tid = blockIdx.x * NTHR + threadIdx.x;

    float accS[CC], accI[CC], accC[CC];
#pragma unroll
    for (int c = 0; c < CC; ++c) { accS[c] = 0.f; accI[c] = 0.f; accC[c] = 0.f; }

    f32x2 xa[CC], xb[CC];
    i32x2 t0, t1, t2, t3;

    // software pipeline: >=1 full tile of loads always outstanding
    issue_tile(xa, t0, logits, targets, tid);
    issue_tile(xb, t1, logits, targets, tid + NTH_TOT);
    proc_tile(xa, t0, accS, accI, accC);
    issue_tile(xa, t2, logits, targets, tid + 2 * NTH_TOT);
    proc_tile(xb, t1, accS, accI, accC);
    issue_tile(xb, t3, logits, targets, tid + 3 * NTH_TOT);
    proc_tile(xa, t2, accS, accI, accC);
    proc_tile(xb, t3, accS, accI, accC);

    // ---- wave-level reduce of the 57 accumulators ----
#pragma unroll
    for (int c = 0; c < CC; ++c) {
        for (int off = 32; off; off >>= 1) {
            accS[c] += __shfl_down(accS[c], off);
            accI[c] += __shfl_down(accI[c], off);
            accC[c] += __shfl_down(accC[c], off);
        }
    }

    __shared__ float s_part[4][64];
    const int wave = threadIdx.x >> 6;
    const int lane = threadIdx.x & 63;
    if (lane == 0) {
#pragma unroll
        for (int c = 0; c < CC; ++c) {
            s_part[wave][c]          = accS[c];
            s_part[wave][CC + c]     = accI[c];
            s_part[wave][2 * CC + c] = accC[c];
        }
    }
    __syncthreads();
    if (threadIdx.x < 3 * CC) {               // 57 device-scope f32 adds per block
        const float v = s_part[0][threadIdx.x] + s_part[1][threadIdx.x]
                      + s_part[2][threadIdx.x] + s_part[3][threadIdx.x];
        atomicAdd(&sums[threadIdx.x], v);
    }
}

__global__ __launch_bounds__(64) void dice_final(
    const float* __restrict__ sums, float* __restrict__ out)
{
    const int c = threadIdx.x;                // one wave
    float term = 0.f, tv = 0.f;
    if (c < CC) {
        const float S = sums[c];
        const float I = sums[CC + c];
        const float N = sums[2 * CC + c];
        tv = N;
        term = 1.f - (2.f * I + 1.f) / (S + N + 1.f);
    }
#pragma unroll
    for (int off = 32; off; off >>= 1) {
        term += __shfl_down(term, off);
        tv   += __shfl_down(tv, off);
    }
    if (c == 0)
        out[0] = (tv > 0.f) ? term * (1.f / (float)CC) : 0.f;
}

extern "C" void kernel_launch(void* const* d_in, const int* in_sizes, int n_in,
                              void* d_out, int out_size, void* d_ws, size_t ws_size,
                              hipStream_t stream) {
    const float* logits = (const float*)d_in[0];
    const int* targets = (const int*)d_in[1];
    float* sums = (float*)d_ws;               // 64 floats used
    float* out = (float*)d_out;

    hipMemsetAsync(sums, 0, 64 * sizeof(float), stream);  // ws is poisoned
    dice_accum<<<NBLK, NTHR, 0, stream>>>(logits, targets, sums);
    dice_final<<<1, 64, 0, stream>>>(sums, out);
}